// Round 1
// baseline (599.925 us; speedup 1.0000x reference)
//
#include <hip/hip_runtime.h>

// Problem constants
#define N     16384
#define DH    64          // feature dim of h
#define TILE  128         // rows/cols per tile
#define NT    (N / TILE)  // 128 tiles per side
#define S     132         // padded LDS stride (floats) for [k][row] layout

// ---------------------------------------------------------------------------
// Stage 128 rows x 32 k (starting at k0) of h-tile (rows r0..r0+127) into LDS
// transposed: dst[k_local*S + row]. Global reads are coalesced float4;
// LDS writes are 4-way bank conflicted (acceptable, staging is small).
// ---------------------------------------------------------------------------
__device__ __forceinline__ void stage_half(const float* __restrict__ h, int r0, int k0,
                                           float* __restrict__ dst, int tid)
{
#pragma unroll
    for (int q = 0; q < 4; ++q) {
        int f4  = tid + 256 * q;   // 0..1023
        int row = f4 >> 3;         // 0..127
        int kq  = f4 & 7;          // 0..7
        const float4 v = *(const float4*)(h + (size_t)(r0 + row) * DH + k0 + 4 * kq);
        int kl = 4 * kq;
        dst[(kl + 0) * S + row] = v.x;
        dst[(kl + 1) * S + row] = v.y;
        dst[(kl + 2) * S + row] = v.z;
        dst[(kl + 3) * S + row] = v.w;
    }
}

// ---------------------------------------------------------------------------
// 32-k inner product accumulation; 8x8 micro-tile per thread with column-split
// halves: rows {4ty..4ty+3, 64+4ty..+3}, cols {4tx..4tx+3, 64+4tx..+3}.
// A-reads: 4 distinct addresses/wave (broadcast, free).
// B-reads: 16 addresses stride 4 words -> 2-way (free).
// ---------------------------------------------------------------------------
__device__ __forceinline__ void compute_k(const float* __restrict__ A, const float* __restrict__ B,
                                          int ty4, int tx4, float g[8][8])
{
#pragma unroll 8
    for (int k = 0; k < 32; ++k) {
        float av[8], bv[8];
        *(float4*)&av[0] = *(const float4*)&A[k * S + ty4];
        *(float4*)&av[4] = *(const float4*)&A[k * S + 64 + ty4];
        *(float4*)&bv[0] = *(const float4*)&B[k * S + tx4];
        *(float4*)&bv[4] = *(const float4*)&B[k * S + 64 + tx4];
#pragma unroll
        for (int ii = 0; ii < 8; ++ii)
#pragma unroll
            for (int jj = 0; jj < 8; ++jj)
                g[ii][jj] = fmaf(av[ii], bv[jj], g[ii][jj]);
    }
}

// ---------------------------------------------------------------------------
// Kernel 1: per-pedestrian MLP. One thread per row; weights staged in LDS
// (uniform-address broadcast reads). Fully unrolled so h1/h2 stay in VGPRs.
// ---------------------------------------------------------------------------
__global__ __launch_bounds__(128) void mlp_kernel(
    const float* __restrict__ data,
    const float* __restrict__ W1, const float* __restrict__ b1,
    const float* __restrict__ W2, const float* __restrict__ b2,
    const float* __restrict__ W3, const float* __restrict__ b3,
    float* __restrict__ hout)
{
    __shared__ float sW1[64], sb1[32], sW2[32 * 64], sb2[64], sW3[64 * 64], sb3[64];
    const int tid = threadIdx.x;
    if (tid < 64) sW1[tid] = W1[tid];
    if (tid < 32) sb1[tid] = b1[tid];
    if (tid < 64) sb2[tid] = b2[tid];
    if (tid < 64) sb3[tid] = b3[tid];
    for (int t = tid; t < 32 * 64; t += 128) sW2[t] = W2[t];
    for (int t = tid; t < 64 * 64; t += 128) sW3[t] = W3[t];
    __syncthreads();

    const int i = blockIdx.x * 128 + tid;
    const float x0 = data[2 * i + 0];
    const float x1 = data[2 * i + 1];

    float h1[32];
#pragma unroll
    for (int o = 0; o < 32; ++o)
        h1[o] = fmaxf(0.f, fmaf(x0, sW1[o], fmaf(x1, sW1[32 + o], sb1[o])));

    float h2[64];
#pragma unroll
    for (int o = 0; o < 64; ++o) {
        float a = sb2[o];
#pragma unroll
        for (int k = 0; k < 32; ++k) a = fmaf(h1[k], sW2[k * 64 + o], a);
        h2[o] = fmaxf(0.f, a);
    }

#pragma unroll
    for (int o = 0; o < 64; ++o) {
        float a = sb3[o];
#pragma unroll
        for (int k = 0; k < 64; ++k) a = fmaf(h2[k], sW3[k * 64 + o], a);
        hout[(size_t)i * DH + o] = a;
    }
}

// ---------------------------------------------------------------------------
// Kernel 2: symmetric pass 1. Block (bi<=bj) computes the 128x128 G-tile once
// and emits per-row (tile-local max, tile-local sum of exp) partials for BOTH
// row-tile bi (over cols of bj) and row-tile bj (over cols of bi, symmetry).
// part arrays are indexed [other_tile][global_row]; every slot written once.
// ---------------------------------------------------------------------------
__global__ __launch_bounds__(256) void pass1_kernel(
    const float* __restrict__ h,
    float* __restrict__ part_m, float* __restrict__ part_l)
{
    const int bj = blockIdx.x, bi = blockIdx.y;
    if (bi > bj) return;

    __shared__ float ldsA[64 * S];
    __shared__ float ldsB[32 * S];

    const int tid = threadIdx.x;
    const int tx = tid & 15, ty = tid >> 4;
    const int tx4 = tx * 4, ty4 = ty * 4;

    float g[8][8];
#pragma unroll
    for (int ii = 0; ii < 8; ++ii)
#pragma unroll
        for (int jj = 0; jj < 8; ++jj) g[ii][jj] = 0.f;

    stage_half(h, bi * TILE, 0,  ldsA, tid);
    stage_half(h, bi * TILE, 32, ldsA + 32 * S, tid);
    stage_half(h, bj * TILE, 0,  ldsB, tid);
    __syncthreads();
    compute_k(ldsA, ldsB, ty4, tx4, g);
    __syncthreads();
    stage_half(h, bj * TILE, 32, ldsB, tid);
    __syncthreads();
    compute_k(ldsA + 32 * S, ldsB, ty4, tx4, g);
    __syncthreads();   // also releases ldsB for reuse as merge buffer

    float* mb = ldsB;          // [128 rows][16]
    float* lb = ldsB + 2048;

    // ---- i-side: stats of rows in tile bi over columns of tile bj ----
#pragma unroll
    for (int ii = 0; ii < 8; ++ii) {
        const int lr = (ii < 4) ? (ty4 + ii) : (64 + ty4 + ii - 4);
        float tm = g[ii][0];
#pragma unroll
        for (int jj = 1; jj < 8; ++jj) tm = fmaxf(tm, g[ii][jj]);
        float s = 0.f;
#pragma unroll
        for (int jj = 0; jj < 8; ++jj) s += __expf(g[ii][jj] - tm);
        mb[lr * 16 + tx] = tm;
        lb[lr * 16 + tx] = s;
    }
    __syncthreads();
    if (tid < 128) {
        float M = mb[tid * 16];
#pragma unroll
        for (int t = 1; t < 16; ++t) M = fmaxf(M, mb[tid * 16 + t]);
        float L = 0.f;
#pragma unroll
        for (int t = 0; t < 16; ++t) L += lb[tid * 16 + t] * __expf(mb[tid * 16 + t] - M);
        part_m[(size_t)bj * N + bi * TILE + tid] = M;
        part_l[(size_t)bj * N + bi * TILE + tid] = L;
    }

    // ---- j-side (only off-diagonal): stats of rows in tile bj over cols of bi ----
    if (bi != bj) {
        __syncthreads();
#pragma unroll
        for (int jj = 0; jj < 8; ++jj) {
            const int lc = (jj < 4) ? (tx4 + jj) : (64 + tx4 + jj - 4);
            float tm = g[0][jj];
#pragma unroll
            for (int ii = 1; ii < 8; ++ii) tm = fmaxf(tm, g[ii][jj]);
            float s = 0.f;
#pragma unroll
            for (int ii = 0; ii < 8; ++ii) s += __expf(g[ii][jj] - tm);
            mb[lc * 16 + ty] = tm;
            lb[lc * 16 + ty] = s;
        }
        __syncthreads();
        if (tid < 128) {
            float M = mb[tid * 16];
#pragma unroll
            for (int t = 1; t < 16; ++t) M = fmaxf(M, mb[tid * 16 + t]);
            float L = 0.f;
#pragma unroll
            for (int t = 0; t < 16; ++t) L += lb[tid * 16 + t] * __expf(mb[tid * 16 + t] - M);
            part_m[(size_t)bi * N + bj * TILE + tid] = M;
            part_l[(size_t)bi * N + bj * TILE + tid] = L;
        }
    }
}

// ---------------------------------------------------------------------------
// Kernel 3: merge 128 partial (m,l) pairs per row -> rowmax m_i, r_i = 1/L.
// ---------------------------------------------------------------------------
__global__ __launch_bounds__(256) void merge_kernel(
    const float* __restrict__ part_m, const float* __restrict__ part_l,
    float* __restrict__ mrow, float* __restrict__ rrow)
{
    const int i = blockIdx.x * 256 + threadIdx.x;
    float M = -3.0e38f;
    for (int o = 0; o < NT; ++o) M = fmaxf(M, part_m[(size_t)o * N + i]);
    float L = 0.f;
    for (int o = 0; o < NT; ++o)
        L = fmaf(part_l[(size_t)o * N + i], __expf(part_m[(size_t)o * N + i] - M), L);
    mrow[i] = M;
    rrow[i] = 1.0f / L;
}

// ---------------------------------------------------------------------------
// Kernel 4: symmetric pass 2. Recompute tile, write softmax values for the
// (bi,bj) tile directly and (if off-diagonal) the mirrored (bj,bi) tile.
// ---------------------------------------------------------------------------
__global__ __launch_bounds__(256) void pass2_kernel(
    const float* __restrict__ h,
    const float* __restrict__ mrow, const float* __restrict__ rrow,
    float* __restrict__ out)
{
    const int bj = blockIdx.x, bi = blockIdx.y;
    if (bi > bj) return;

    __shared__ float ldsA[64 * S];
    __shared__ float ldsB[32 * S];

    const int tid = threadIdx.x;
    const int tx = tid & 15, ty = tid >> 4;
    const int tx4 = tx * 4, ty4 = ty * 4;

    float g[8][8];
#pragma unroll
    for (int ii = 0; ii < 8; ++ii)
#pragma unroll
        for (int jj = 0; jj < 8; ++jj) g[ii][jj] = 0.f;

    stage_half(h, bi * TILE, 0,  ldsA, tid);
    stage_half(h, bi * TILE, 32, ldsA + 32 * S, tid);
    stage_half(h, bj * TILE, 0,  ldsB, tid);
    __syncthreads();
    compute_k(ldsA, ldsB, ty4, tx4, g);
    __syncthreads();
    stage_half(h, bj * TILE, 32, ldsB, tid);
    __syncthreads();
    compute_k(ldsA + 32 * S, ldsB, ty4, tx4, g);

    // row stats for this thread's 8 rows (tile bi) and 8 cols (tile bj)
    float mi[8], ri[8], mj[8], rj[8];
#pragma unroll
    for (int ii = 0; ii < 8; ++ii) {
        const int r = bi * TILE + ((ii < 4) ? (ty4 + ii) : (64 + ty4 + ii - 4));
        mi[ii] = mrow[r];
        ri[ii] = rrow[r];
    }
#pragma unroll
    for (int jj = 0; jj < 8; ++jj) {
        const int c = bj * TILE + ((jj < 4) ? (tx4 + jj) : (64 + tx4 + jj - 4));
        mj[jj] = mrow[c];
        rj[jj] = rrow[c];
    }

    // direct tile: rows of bi, cols of bj
#pragma unroll
    for (int ii = 0; ii < 8; ++ii) {
        const int lr = (ii < 4) ? (ty4 + ii) : (64 + ty4 + ii - 4);
        float4 v0, v1;
        v0.x = __expf(g[ii][0] - mi[ii]) * ri[ii];
        v0.y = __expf(g[ii][1] - mi[ii]) * ri[ii];
        v0.z = __expf(g[ii][2] - mi[ii]) * ri[ii];
        v0.w = __expf(g[ii][3] - mi[ii]) * ri[ii];
        v1.x = __expf(g[ii][4] - mi[ii]) * ri[ii];
        v1.y = __expf(g[ii][5] - mi[ii]) * ri[ii];
        v1.z = __expf(g[ii][6] - mi[ii]) * ri[ii];
        v1.w = __expf(g[ii][7] - mi[ii]) * ri[ii];
        const size_t base = (size_t)(bi * TILE + lr) * N + bj * TILE + tx4;
        *(float4*)(out + base)      = v0;
        *(float4*)(out + base + 64) = v1;
    }

    // mirrored tile: rows of bj, cols of bi
    if (bi != bj) {
#pragma unroll
        for (int jj = 0; jj < 8; ++jj) {
            const int lc = (jj < 4) ? (tx4 + jj) : (64 + tx4 + jj - 4);
            float4 v0, v1;
            v0.x = __expf(g[0][jj] - mj[jj]) * rj[jj];
            v0.y = __expf(g[1][jj] - mj[jj]) * rj[jj];
            v0.z = __expf(g[2][jj] - mj[jj]) * rj[jj];
            v0.w = __expf(g[3][jj] - mj[jj]) * rj[jj];
            v1.x = __expf(g[4][jj] - mj[jj]) * rj[jj];
            v1.y = __expf(g[5][jj] - mj[jj]) * rj[jj];
            v1.z = __expf(g[6][jj] - mj[jj]) * rj[jj];
            v1.w = __expf(g[7][jj] - mj[jj]) * rj[jj];
            const size_t base = (size_t)(bj * TILE + lc) * N + bi * TILE + ty4;
            *(float4*)(out + base)      = v0;
            *(float4*)(out + base + 64) = v1;
        }
    }
}

// ---------------------------------------------------------------------------
extern "C" void kernel_launch(void* const* d_in, const int* in_sizes, int n_in,
                              void* d_out, int out_size, void* d_ws, size_t ws_size,
                              hipStream_t stream)
{
    const float* data = (const float*)d_in[0];
    const float* W1   = (const float*)d_in[1];
    const float* b1   = (const float*)d_in[2];
    const float* W2   = (const float*)d_in[3];
    const float* b2   = (const float*)d_in[4];
    const float* W3   = (const float*)d_in[5];
    const float* b3   = (const float*)d_in[6];
    float* out = (float*)d_out;

    // workspace layout (floats): h[N*64] | part_m[NT*N] | part_l[NT*N] | mrow[N] | rrow[N]
    float* h      = (float*)d_ws;
    float* part_m = h + (size_t)N * DH;
    float* part_l = part_m + (size_t)NT * N;
    float* mrow   = part_l + (size_t)NT * N;
    float* rrow   = mrow + N;

    mlp_kernel<<<N / 128, 128, 0, stream>>>(data, W1, b1, W2, b2, W3, b3, h);
    pass1_kernel<<<dim3(NT, NT), 256, 0, stream>>>(h, part_m, part_l);
    merge_kernel<<<N / 256, 256, 0, stream>>>(part_m, part_l, mrow, rrow);
    pass2_kernel<<<dim3(NT, NT), 256, 0, stream>>>(h, mrow, rrow, out);
}

// Round 2
// 598.055 us; speedup vs baseline: 1.0031x; 1.0031x over previous
//
#include <hip/hip_runtime.h>

#define N     16384
#define DH    64
#define TILE  128
#define NT    (N / TILE)

typedef __attribute__((ext_vector_type(8))) short  short8;
typedef __attribute__((ext_vector_type(4))) float  f32x4;

// ---- bf16 helpers (round-to-nearest-even) --------------------------------
__device__ __forceinline__ ushort bf_hi(float x) {
    unsigned u = __float_as_uint(x);
    unsigned r = u + 0x7FFFu + ((u >> 16) & 1u);
    return (ushort)(r >> 16);
}
__device__ __forceinline__ float bf_val(ushort h) {
    return __uint_as_float(((unsigned)h) << 16);
}

// per-lane 16B fragment load: 8 contiguous bf16 features of one h-row
__device__ __forceinline__ short8 ldfrag(const ushort* __restrict__ p, int row, int koff) {
    return *(const short8*)(p + (size_t)row * DH + koff);
}

// ---------------------------------------------------------------------------
// Kernel 1: per-pedestrian MLP -> h split into bf16 hi/lo pair (hi+lo ~ fp32).
// ---------------------------------------------------------------------------
__global__ __launch_bounds__(128) void mlp_kernel(
    const float* __restrict__ data,
    const float* __restrict__ W1, const float* __restrict__ b1,
    const float* __restrict__ W2, const float* __restrict__ b2,
    const float* __restrict__ W3, const float* __restrict__ b3,
    ushort* __restrict__ hHi, ushort* __restrict__ hLo)
{
    __shared__ float sW1[64], sb1[32], sW2[32 * 64], sb2[64], sW3[64 * 64], sb3[64];
    const int tid = threadIdx.x;
    if (tid < 64) sW1[tid] = W1[tid];
    if (tid < 32) sb1[tid] = b1[tid];
    if (tid < 64) sb2[tid] = b2[tid];
    if (tid < 64) sb3[tid] = b3[tid];
    for (int t = tid; t < 32 * 64; t += 128) sW2[t] = W2[t];
    for (int t = tid; t < 64 * 64; t += 128) sW3[t] = W3[t];
    __syncthreads();

    const int i = blockIdx.x * 128 + tid;
    const float x0 = data[2 * i + 0];
    const float x1 = data[2 * i + 1];

    float h1[32];
#pragma unroll
    for (int o = 0; o < 32; ++o)
        h1[o] = fmaxf(0.f, fmaf(x0, sW1[o], fmaf(x1, sW1[32 + o], sb1[o])));

    float h2[64];
#pragma unroll
    for (int o = 0; o < 64; ++o) {
        float a = sb2[o];
#pragma unroll
        for (int k = 0; k < 32; ++k) a = fmaf(h1[k], sW2[k * 64 + o], a);
        h2[o] = fmaxf(0.f, a);
    }

    ushort hs[64], ls[64];
#pragma unroll
    for (int o = 0; o < 64; ++o) {
        float a = sb3[o];
#pragma unroll
        for (int k = 0; k < 64; ++k) a = fmaf(h2[k], sW3[k * 64 + o], a);
        const ushort hb = bf_hi(a);
        hs[o] = hb;
        ls[o] = bf_hi(a - bf_val(hb));
    }
#pragma unroll
    for (int q = 0; q < 8; ++q) {
        short8 vh, vl;
#pragma unroll
        for (int t = 0; t < 8; ++t) { vh[t] = (short)hs[q * 8 + t]; vl[t] = (short)ls[q * 8 + t]; }
        *(short8*)(hHi + (size_t)i * DH + q * 8) = vh;
        *(short8*)(hLo + (size_t)i * DH + q * 8) = vl;
    }
}

// ---------------------------------------------------------------------------
// Shared MFMA tile computation: 128x128 G-tile, 4 waves x (32-row strip).
// acc[rb][cb] is a 16x16 fragment; C layout: col = lane&15, row = (lane>>4)*4+reg.
// G = hiA*hiB + hiA*loB + loA*hiB  (lo*lo dropped, ~2^-18 relative).
// ---------------------------------------------------------------------------
__device__ __forceinline__ void gram_tile(
    const ushort* __restrict__ hHi, const ushort* __restrict__ hLo,
    int bi, int bj, int wave, int r16, int kb, f32x4 acc[2][8])
{
#pragma unroll
    for (int rb = 0; rb < 2; ++rb)
#pragma unroll
        for (int cb = 0; cb < 8; ++cb) acc[rb][cb] = (f32x4){0.f, 0.f, 0.f, 0.f};

    const int arow = bi * TILE + wave * 32 + r16;
    short8 Ah[2][2], Al[2][2];
#pragma unroll
    for (int rb = 0; rb < 2; ++rb)
#pragma unroll
        for (int ks = 0; ks < 2; ++ks) {
            Ah[rb][ks] = ldfrag(hHi, arow + rb * 16, ks * 32 + kb * 8);
            Al[rb][ks] = ldfrag(hLo, arow + rb * 16, ks * 32 + kb * 8);
        }

    const int brow = bj * TILE + r16;
#pragma unroll
    for (int cb = 0; cb < 8; ++cb) {
        short8 Bh[2], Bl[2];
#pragma unroll
        for (int ks = 0; ks < 2; ++ks) {
            Bh[ks] = ldfrag(hHi, brow + cb * 16, ks * 32 + kb * 8);
            Bl[ks] = ldfrag(hLo, brow + cb * 16, ks * 32 + kb * 8);
        }
#pragma unroll
        for (int rb = 0; rb < 2; ++rb)
#pragma unroll
            for (int ks = 0; ks < 2; ++ks) {
                acc[rb][cb] = __builtin_amdgcn_mfma_f32_16x16x32_bf16(Ah[rb][ks], Bh[ks], acc[rb][cb], 0, 0, 0);
                acc[rb][cb] = __builtin_amdgcn_mfma_f32_16x16x32_bf16(Ah[rb][ks], Bl[ks], acc[rb][cb], 0, 0, 0);
                acc[rb][cb] = __builtin_amdgcn_mfma_f32_16x16x32_bf16(Al[rb][ks], Bh[ks], acc[rb][cb], 0, 0, 0);
            }
    }
}

// ---------------------------------------------------------------------------
// Kernel 2: symmetric pass 1 (bi<=bj). Emits per-row (tile max, tile sum-exp)
// partials for row-tile bi over cols bj (i-side, pure shuffle reduce) and, if
// off-diagonal, for row-tile bj over cols bi (j-side, shuffle + tiny LDS).
// ---------------------------------------------------------------------------
__global__ __launch_bounds__(256) void pass1_mfma(
    const ushort* __restrict__ hHi, const ushort* __restrict__ hLo,
    float* __restrict__ part_m, float* __restrict__ part_l)
{
    const int bj = blockIdx.x, bi = blockIdx.y;
    if (bi > bj) return;

    __shared__ float jm[4][128], jl[4][128];

    const int tid = threadIdx.x;
    const int wave = tid >> 6, lane = tid & 63;
    const int r16 = lane & 15, kb = lane >> 4;

    f32x4 acc[2][8];
    gram_tile(hHi, hLo, bi, bj, wave, r16, kb, acc);

    // ---- i-side: rows of tile bi (this thread's 8 rows) over 128 cols ----
#pragma unroll
    for (int rb = 0; rb < 2; ++rb) {
#pragma unroll
        for (int reg = 0; reg < 4; ++reg) {
            float m = acc[rb][0][reg];
#pragma unroll
            for (int cb = 1; cb < 8; ++cb) m = fmaxf(m, acc[rb][cb][reg]);
            m = fmaxf(m, __shfl_xor(m, 1));
            m = fmaxf(m, __shfl_xor(m, 2));
            m = fmaxf(m, __shfl_xor(m, 4));
            m = fmaxf(m, __shfl_xor(m, 8));
            float s = 0.f;
#pragma unroll
            for (int cb = 0; cb < 8; ++cb) s += __expf(acc[rb][cb][reg] - m);
            s += __shfl_xor(s, 1);
            s += __shfl_xor(s, 2);
            s += __shfl_xor(s, 4);
            s += __shfl_xor(s, 8);
            if (r16 == 0) {
                const int grow = bi * TILE + wave * 32 + rb * 16 + kb * 4 + reg;
                part_m[(size_t)bj * N + grow] = m;
                part_l[(size_t)bj * N + grow] = s;
            }
        }
    }

    // ---- j-side: rows of tile bj (tile columns) over cols of tile bi ----
    if (bi != bj) {
#pragma unroll
        for (int cb = 0; cb < 8; ++cb) {
            float m = acc[0][cb][0];
#pragma unroll
            for (int rb = 0; rb < 2; ++rb)
#pragma unroll
                for (int reg = 0; reg < 4; ++reg) m = fmaxf(m, acc[rb][cb][reg]);
            m = fmaxf(m, __shfl_xor(m, 16));
            m = fmaxf(m, __shfl_xor(m, 32));
            float s = 0.f;
#pragma unroll
            for (int rb = 0; rb < 2; ++rb)
#pragma unroll
                for (int reg = 0; reg < 4; ++reg) s += __expf(acc[rb][cb][reg] - m);
            s += __shfl_xor(s, 16);
            s += __shfl_xor(s, 32);
            if (kb == 0) { jm[wave][cb * 16 + r16] = m; jl[wave][cb * 16 + r16] = s; }
        }
        __syncthreads();
        if (tid < 128) {
            float M = jm[0][tid];
#pragma unroll
            for (int w = 1; w < 4; ++w) M = fmaxf(M, jm[w][tid]);
            float L = 0.f;
#pragma unroll
            for (int w = 0; w < 4; ++w) L += jl[w][tid] * __expf(jm[w][tid] - M);
            part_m[(size_t)bi * N + bj * TILE + tid] = M;
            part_l[(size_t)bi * N + bj * TILE + tid] = L;
        }
    }
}

// ---------------------------------------------------------------------------
// Kernel 3: merge 128 partial (m,l) per row -> rowmax m_i, r_i = 1/L.
// ---------------------------------------------------------------------------
__global__ __launch_bounds__(256) void merge_kernel(
    const float* __restrict__ part_m, const float* __restrict__ part_l,
    float* __restrict__ mrow, float* __restrict__ rrow)
{
    const int i = blockIdx.x * 256 + threadIdx.x;
    float M = -3.0e38f;
    for (int o = 0; o < NT; ++o) M = fmaxf(M, part_m[(size_t)o * N + i]);
    float L = 0.f;
    for (int o = 0; o < NT; ++o)
        L = fmaf(part_l[(size_t)o * N + i], __expf(part_m[(size_t)o * N + i] - M), L);
    mrow[i] = M;
    rrow[i] = 1.0f / L;
}

// ---------------------------------------------------------------------------
// Kernel 4: pass 2, full grid. Recompute each tile with MFMA and write
// exp(g - m_row) * r_row with perfectly coalesced stores.
// ---------------------------------------------------------------------------
__global__ __launch_bounds__(256) void pass2_mfma(
    const ushort* __restrict__ hHi, const ushort* __restrict__ hLo,
    const float* __restrict__ mrow, const float* __restrict__ rrow,
    float* __restrict__ out)
{
    const int bj = blockIdx.x, bi = blockIdx.y;
    const int tid = threadIdx.x;
    const int wave = tid >> 6, lane = tid & 63;
    const int r16 = lane & 15, kb = lane >> 4;

    f32x4 acc[2][8];
    gram_tile(hHi, hLo, bi, bj, wave, r16, kb, acc);

    float mv[2][4], rv[2][4];
#pragma unroll
    for (int rb = 0; rb < 2; ++rb)
#pragma unroll
        for (int reg = 0; reg < 4; ++reg) {
            const int grow = bi * TILE + wave * 32 + rb * 16 + kb * 4 + reg;
            mv[rb][reg] = mrow[grow];
            rv[rb][reg] = rrow[grow];
        }

#pragma unroll
    for (int rb = 0; rb < 2; ++rb)
#pragma unroll
        for (int reg = 0; reg < 4; ++reg) {
            const int grow = bi * TILE + wave * 32 + rb * 16 + kb * 4 + reg;
            const size_t base = (size_t)grow * N + bj * TILE + r16;
#pragma unroll
            for (int cb = 0; cb < 8; ++cb)
                out[base + cb * 16] = __expf(acc[rb][cb][reg] - mv[rb][reg]) * rv[rb][reg];
        }
}

// ---------------------------------------------------------------------------
extern "C" void kernel_launch(void* const* d_in, const int* in_sizes, int n_in,
                              void* d_out, int out_size, void* d_ws, size_t ws_size,
                              hipStream_t stream)
{
    const float* data = (const float*)d_in[0];
    const float* W1   = (const float*)d_in[1];
    const float* b1   = (const float*)d_in[2];
    const float* W2   = (const float*)d_in[3];
    const float* b2   = (const float*)d_in[4];
    const float* W3   = (const float*)d_in[5];
    const float* b3   = (const float*)d_in[6];
    float* out = (float*)d_out;

    // workspace: part_m[NT*N] | part_l[NT*N] | mrow[N] | rrow[N] | hHi[N*64] | hLo[N*64]
    float* part_m = (float*)d_ws;
    float* part_l = part_m + (size_t)NT * N;
    float* mrow   = part_l + (size_t)NT * N;
    float* rrow   = mrow + N;
    ushort* hHi   = (ushort*)(rrow + N);
    ushort* hLo   = hHi + (size_t)N * DH;

    mlp_kernel<<<N / 128, 128, 0, stream>>>(data, W1, b1, W2, b2, W3, b3, hHi, hLo);
    pass1_mfma<<<dim3(NT, NT), 256, 0, stream>>>(hHi, hLo, part_m, part_l);
    merge_kernel<<<N / 256, 256, 0, stream>>>(part_m, part_l, mrow, rrow);
    pass2_mfma<<<dim3(NT, NT), 256, 0, stream>>>(hHi, hLo, mrow, rrow, out);
}

// Round 4
// 573.872 us; speedup vs baseline: 1.0454x; 1.0421x over previous
//
#include <hip/hip_runtime.h>

#define N     16384
#define DH    64
#define TILE  128
#define NT    (N / TILE)
#define S2    133   // padded LDS stride for the P-tile staging buffer

typedef __attribute__((ext_vector_type(8))) short  short8;
typedef __attribute__((ext_vector_type(4))) float  f32x4;

// ---- bf16 helpers (round-to-nearest-even) --------------------------------
__device__ __forceinline__ ushort bf_hi(float x) {
    unsigned u = __float_as_uint(x);
    unsigned r = u + 0x7FFFu + ((u >> 16) & 1u);
    return (ushort)(r >> 16);
}
__device__ __forceinline__ float bf_val(ushort h) {
    return __uint_as_float(((unsigned)h) << 16);
}

// per-lane 16B fragment load: 8 contiguous bf16 features of one h-row
__device__ __forceinline__ short8 ldfrag(const ushort* __restrict__ p, int row, int koff) {
    return *(const short8*)(p + (size_t)row * DH + koff);
}

// ---------------------------------------------------------------------------
// Kernel 1: per-pedestrian MLP -> h split into bf16 hi/lo pair (hi+lo ~ fp32).
// ---------------------------------------------------------------------------
__global__ __launch_bounds__(128) void mlp_kernel(
    const float* __restrict__ data,
    const float* __restrict__ W1, const float* __restrict__ b1,
    const float* __restrict__ W2, const float* __restrict__ b2,
    const float* __restrict__ W3, const float* __restrict__ b3,
    ushort* __restrict__ hHi, ushort* __restrict__ hLo)
{
    __shared__ float sW1[64], sb1[32], sW2[32 * 64], sb2[64], sW3[64 * 64], sb3[64];
    const int tid = threadIdx.x;
    if (tid < 64) sW1[tid] = W1[tid];
    if (tid < 32) sb1[tid] = b1[tid];
    if (tid < 64) sb2[tid] = b2[tid];
    if (tid < 64) sb3[tid] = b3[tid];
    for (int t = tid; t < 32 * 64; t += 128) sW2[t] = W2[t];
    for (int t = tid; t < 64 * 64; t += 128) sW3[t] = W3[t];
    __syncthreads();

    const int i = blockIdx.x * 128 + tid;
    const float x0 = data[2 * i + 0];
    const float x1 = data[2 * i + 1];

    float h1[32];
#pragma unroll
    for (int o = 0; o < 32; ++o)
        h1[o] = fmaxf(0.f, fmaf(x0, sW1[o], fmaf(x1, sW1[32 + o], sb1[o])));

    float h2[64];
#pragma unroll
    for (int o = 0; o < 64; ++o) {
        float a = sb2[o];
#pragma unroll
        for (int k = 0; k < 32; ++k) a = fmaf(h1[k], sW2[k * 64 + o], a);
        h2[o] = fmaxf(0.f, a);
    }

    ushort hs[64], ls[64];
#pragma unroll
    for (int o = 0; o < 64; ++o) {
        float a = sb3[o];
#pragma unroll
        for (int k = 0; k < 64; ++k) a = fmaf(h2[k], sW3[k * 64 + o], a);
        const ushort hb = bf_hi(a);
        hs[o] = hb;
        ls[o] = bf_hi(a - bf_val(hb));
    }
#pragma unroll
    for (int q = 0; q < 8; ++q) {
        short8 vh, vl;
#pragma unroll
        for (int t = 0; t < 8; ++t) { vh[t] = (short)hs[q * 8 + t]; vl[t] = (short)ls[q * 8 + t]; }
        *(short8*)(hHi + (size_t)i * DH + q * 8) = vh;
        *(short8*)(hLo + (size_t)i * DH + q * 8) = vl;
    }
}

// ---------------------------------------------------------------------------
// Shared MFMA tile computation: 128x128 G-tile, 4 waves x (32-row strip).
// acc[rb][cb] is a 16x16 fragment; C layout: col = lane&15, row = (lane>>4)*4+reg.
// G = hiA*hiB + hiA*loB + loA*hiB  (lo*lo dropped, ~2^-18 relative).
// ---------------------------------------------------------------------------
__device__ __forceinline__ void gram_tile(
    const ushort* __restrict__ hHi, const ushort* __restrict__ hLo,
    int bi, int bj, int wave, int r16, int kb, f32x4 acc[2][8])
{
#pragma unroll
    for (int rb = 0; rb < 2; ++rb)
#pragma unroll
        for (int cb = 0; cb < 8; ++cb) acc[rb][cb] = (f32x4){0.f, 0.f, 0.f, 0.f};

    const int arow = bi * TILE + wave * 32 + r16;
    short8 Ah[2][2], Al[2][2];
#pragma unroll
    for (int rb = 0; rb < 2; ++rb)
#pragma unroll
        for (int ks = 0; ks < 2; ++ks) {
            Ah[rb][ks] = ldfrag(hHi, arow + rb * 16, ks * 32 + kb * 8);
            Al[rb][ks] = ldfrag(hLo, arow + rb * 16, ks * 32 + kb * 8);
        }

    const int brow = bj * TILE + r16;
#pragma unroll
    for (int cb = 0; cb < 8; ++cb) {
        short8 Bh[2], Bl[2];
#pragma unroll
        for (int ks = 0; ks < 2; ++ks) {
            Bh[ks] = ldfrag(hHi, brow + cb * 16, ks * 32 + kb * 8);
            Bl[ks] = ldfrag(hLo, brow + cb * 16, ks * 32 + kb * 8);
        }
#pragma unroll
        for (int rb = 0; rb < 2; ++rb)
#pragma unroll
            for (int ks = 0; ks < 2; ++ks) {
                acc[rb][cb] = __builtin_amdgcn_mfma_f32_16x16x32_bf16(Ah[rb][ks], Bh[ks], acc[rb][cb], 0, 0, 0);
                acc[rb][cb] = __builtin_amdgcn_mfma_f32_16x16x32_bf16(Ah[rb][ks], Bl[ks], acc[rb][cb], 0, 0, 0);
                acc[rb][cb] = __builtin_amdgcn_mfma_f32_16x16x32_bf16(Al[rb][ks], Bh[ks], acc[rb][cb], 0, 0, 0);
            }
    }
}

// ---------------------------------------------------------------------------
// Kernel 2: symmetric pass 1 (bi<=bj). Emits per-row (tile max, tile sum-exp)
// partials for row-tile bi over cols bj (i-side, pure shuffle reduce) and, if
// off-diagonal, for row-tile bj over cols bi (j-side, shuffle + tiny LDS).
// ---------------------------------------------------------------------------
__global__ __launch_bounds__(256) void pass1_mfma(
    const ushort* __restrict__ hHi, const ushort* __restrict__ hLo,
    float* __restrict__ part_m, float* __restrict__ part_l)
{
    const int bj = blockIdx.x, bi = blockIdx.y;
    if (bi > bj) return;

    __shared__ float jm[4][128], jl[4][128];

    const int tid = threadIdx.x;
    const int wave = tid >> 6, lane = tid & 63;
    const int r16 = lane & 15, kb = lane >> 4;

    f32x4 acc[2][8];
    gram_tile(hHi, hLo, bi, bj, wave, r16, kb, acc);

    // ---- i-side: rows of tile bi (this thread's 8 rows) over 128 cols ----
#pragma unroll
    for (int rb = 0; rb < 2; ++rb) {
#pragma unroll
        for (int reg = 0; reg < 4; ++reg) {
            float m = acc[rb][0][reg];
#pragma unroll
            for (int cb = 1; cb < 8; ++cb) m = fmaxf(m, acc[rb][cb][reg]);
            m = fmaxf(m, __shfl_xor(m, 1));
            m = fmaxf(m, __shfl_xor(m, 2));
            m = fmaxf(m, __shfl_xor(m, 4));
            m = fmaxf(m, __shfl_xor(m, 8));
            float s = 0.f;
#pragma unroll
            for (int cb = 0; cb < 8; ++cb) s += __expf(acc[rb][cb][reg] - m);
            s += __shfl_xor(s, 1);
            s += __shfl_xor(s, 2);
            s += __shfl_xor(s, 4);
            s += __shfl_xor(s, 8);
            if (r16 == 0) {
                const int grow = bi * TILE + wave * 32 + rb * 16 + kb * 4 + reg;
                part_m[(size_t)bj * N + grow] = m;
                part_l[(size_t)bj * N + grow] = s;
            }
        }
    }

    // ---- j-side: rows of tile bj (tile columns) over cols of tile bi ----
    if (bi != bj) {
#pragma unroll
        for (int cb = 0; cb < 8; ++cb) {
            float m = acc[0][cb][0];
#pragma unroll
            for (int rb = 0; rb < 2; ++rb)
#pragma unroll
                for (int reg = 0; reg < 4; ++reg) m = fmaxf(m, acc[rb][cb][reg]);
            m = fmaxf(m, __shfl_xor(m, 16));
            m = fmaxf(m, __shfl_xor(m, 32));
            float s = 0.f;
#pragma unroll
            for (int rb = 0; rb < 2; ++rb)
#pragma unroll
                for (int reg = 0; reg < 4; ++reg) s += __expf(acc[rb][cb][reg] - m);
            s += __shfl_xor(s, 16);
            s += __shfl_xor(s, 32);
            if (kb == 0) { jm[wave][cb * 16 + r16] = m; jl[wave][cb * 16 + r16] = s; }
        }
        __syncthreads();
        if (tid < 128) {
            float M = jm[0][tid];
#pragma unroll
            for (int w = 1; w < 4; ++w) M = fmaxf(M, jm[w][tid]);
            float L = 0.f;
#pragma unroll
            for (int w = 0; w < 4; ++w) L += jl[w][tid] * __expf(jm[w][tid] - M);
            part_m[(size_t)bi * N + bj * TILE + tid] = M;
            part_l[(size_t)bi * N + bj * TILE + tid] = L;
        }
    }
}

// ---------------------------------------------------------------------------
// Kernel 3: merge 128 partial (m,l) per row -> rowmax m_i, r_i = 1/L.
// ---------------------------------------------------------------------------
__global__ __launch_bounds__(256) void merge_kernel(
    const float* __restrict__ part_m, const float* __restrict__ part_l,
    float* __restrict__ mrow, float* __restrict__ rrow)
{
    const int i = blockIdx.x * 256 + threadIdx.x;
    float M = -3.0e38f;
    for (int o = 0; o < NT; ++o) M = fmaxf(M, part_m[(size_t)o * N + i]);
    float L = 0.f;
    for (int o = 0; o < NT; ++o)
        L = fmaf(part_l[(size_t)o * N + i], __expf(part_m[(size_t)o * N + i] - M), L);
    mrow[i] = M;
    rrow[i] = 1.0f / L;
}

// ---------------------------------------------------------------------------
// Kernel 4: pass 2, full grid. Recompute each tile with MFMA, apply
// exp(g - m_row) * r_row, stage the P-tile in LDS (64-row halves), and write
// with contiguous 512B/wave float4 NONTEMPORAL stores (no L2 write-allocate).
// ---------------------------------------------------------------------------
__global__ __launch_bounds__(256) void pass2_mfma(
    const ushort* __restrict__ hHi, const ushort* __restrict__ hLo,
    const float* __restrict__ mrow, const float* __restrict__ rrow,
    float* __restrict__ out)
{
    const int bj = blockIdx.x, bi = blockIdx.y;
    const int tid = threadIdx.x;
    const int wave = tid >> 6, lane = tid & 63;
    const int r16 = lane & 15, kb = lane >> 4;

    __shared__ float ldsP[64 * S2];

    f32x4 acc[2][8];
    gram_tile(hHi, hLo, bi, bj, wave, r16, kb, acc);

#pragma unroll
    for (int hh = 0; hh < 2; ++hh) {
        if ((wave >> 1) == hh) {  // waves 2hh,2hh+1 own rows [hh*64, hh*64+64)
#pragma unroll
            for (int rb = 0; rb < 2; ++rb)
#pragma unroll
                for (int reg = 0; reg < 4; ++reg) {
                    const int rtile = wave * 32 + rb * 16 + kb * 4 + reg;
                    const int grow  = bi * TILE + rtile;
                    const float m = mrow[grow];
                    const float r = rrow[grow];
                    const int rl = rtile - hh * 64;
#pragma unroll
                    for (int cb = 0; cb < 8; ++cb)
                        ldsP[rl * S2 + cb * 16 + r16] = __expf(acc[rb][cb][reg] - m) * r;
                }
        }
        __syncthreads();
        // coalesced streaming store: 2048 float4 = 64 rows x 32 float4
#pragma unroll
        for (int q = 0; q < 8; ++q) {
            const int f4 = tid + 256 * q;
            const int rl = f4 >> 5, c4 = f4 & 31;
            const f32x4 v = *(const f32x4*)&ldsP[rl * S2 + c4 * 4];
            f32x4* dst = (f32x4*)(out + (size_t)(bi * TILE + hh * 64 + rl) * N + bj * TILE + c4 * 4);
            __builtin_nontemporal_store(v, dst);
        }
        __syncthreads();
    }
}

// ---------------------------------------------------------------------------
extern "C" void kernel_launch(void* const* d_in, const int* in_sizes, int n_in,
                              void* d_out, int out_size, void* d_ws, size_t ws_size,
                              hipStream_t stream)
{
    const float* data = (const float*)d_in[0];
    const float* W1   = (const float*)d_in[1];
    const float* b1   = (const float*)d_in[2];
    const float* W2   = (const float*)d_in[3];
    const float* b2   = (const float*)d_in[4];
    const float* W3   = (const float*)d_in[5];
    const float* b3   = (const float*)d_in[6];
    float* out = (float*)d_out;

    // workspace: part_m[NT*N] | part_l[NT*N] | mrow[N] | rrow[N] | hHi[N*64] | hLo[N*64]
    float* part_m = (float*)d_ws;
    float* part_l = part_m + (size_t)NT * N;
    float* mrow   = part_l + (size_t)NT * N;
    float* rrow   = mrow + N;
    ushort* hHi   = (ushort*)(rrow + N);
    ushort* hLo   = hHi + (size_t)N * DH;

    mlp_kernel<<<N / 128, 128, 0, stream>>>(data, W1, b1, W2, b2, W3, b3, hHi, hLo);
    pass1_mfma<<<dim3(NT, NT), 256, 0, stream>>>(hHi, hLo, part_m, part_l);
    merge_kernel<<<N / 256, 256, 0, stream>>>(part_m, part_l, mrow, rrow);
    pass2_mfma<<<dim3(NT, NT), 256, 0, stream>>>(hHi, hLo, mrow, rrow, out);
}

// Round 5
// 543.996 us; speedup vs baseline: 1.1028x; 1.0549x over previous
//
#include <hip/hip_runtime.h>

#define N     16384
#define DH    64
#define TILE  128
#define NT    (N / TILE)
#define S2    133   // padded LDS stride for the P-tile staging buffer

typedef __attribute__((ext_vector_type(8))) short  short8;
typedef __attribute__((ext_vector_type(4))) float  f32x4;

// ---- bf16 helpers (round-to-nearest-even) --------------------------------
__device__ __forceinline__ ushort bf_hi(float x) {
    unsigned u = __float_as_uint(x);
    unsigned r = u + 0x7FFFu + ((u >> 16) & 1u);
    return (ushort)(r >> 16);
}
__device__ __forceinline__ float bf_val(ushort h) {
    return __uint_as_float(((unsigned)h) << 16);
}

// per-lane 16B fragment load: 8 contiguous bf16 features of one h-row
__device__ __forceinline__ short8 ldfrag(const ushort* __restrict__ p, int row, int koff) {
    return *(const short8*)(p + (size_t)row * DH + koff);
}

// ---------------------------------------------------------------------------
// Kernel 1: per-pedestrian MLP -> h split into bf16 hi/lo pair (hi+lo ~ fp32).
// ---------------------------------------------------------------------------
__global__ __launch_bounds__(128) void mlp_kernel(
    const float* __restrict__ data,
    const float* __restrict__ W1, const float* __restrict__ b1,
    const float* __restrict__ W2, const float* __restrict__ b2,
    const float* __restrict__ W3, const float* __restrict__ b3,
    ushort* __restrict__ hHi, ushort* __restrict__ hLo)
{
    __shared__ float sW1[64], sb1[32], sW2[32 * 64], sb2[64], sW3[64 * 64], sb3[64];
    const int tid = threadIdx.x;
    if (tid < 64) sW1[tid] = W1[tid];
    if (tid < 32) sb1[tid] = b1[tid];
    if (tid < 64) sb2[tid] = b2[tid];
    if (tid < 64) sb3[tid] = b3[tid];
    for (int t = tid; t < 32 * 64; t += 128) sW2[t] = W2[t];
    for (int t = tid; t < 64 * 64; t += 128) sW3[t] = W3[t];
    __syncthreads();

    const int i = blockIdx.x * 128 + tid;
    const float x0 = data[2 * i + 0];
    const float x1 = data[2 * i + 1];

    float h1[32];
#pragma unroll
    for (int o = 0; o < 32; ++o)
        h1[o] = fmaxf(0.f, fmaf(x0, sW1[o], fmaf(x1, sW1[32 + o], sb1[o])));

    float h2[64];
#pragma unroll
    for (int o = 0; o < 64; ++o) {
        float a = sb2[o];
#pragma unroll
        for (int k = 0; k < 32; ++k) a = fmaf(h1[k], sW2[k * 64 + o], a);
        h2[o] = fmaxf(0.f, a);
    }

    ushort hs[64], ls[64];
#pragma unroll
    for (int o = 0; o < 64; ++o) {
        float a = sb3[o];
#pragma unroll
        for (int k = 0; k < 64; ++k) a = fmaf(h2[k], sW3[k * 64 + o], a);
        const ushort hb = bf_hi(a);
        hs[o] = hb;
        ls[o] = bf_hi(a - bf_val(hb));
    }
#pragma unroll
    for (int q = 0; q < 8; ++q) {
        short8 vh, vl;
#pragma unroll
        for (int t = 0; t < 8; ++t) { vh[t] = (short)hs[q * 8 + t]; vl[t] = (short)ls[q * 8 + t]; }
        *(short8*)(hHi + (size_t)i * DH + q * 8) = vh;
        *(short8*)(hLo + (size_t)i * DH + q * 8) = vl;
    }
}

// ---------------------------------------------------------------------------
// Shared MFMA tile computation: 128x128 G-tile, 4 waves x (32-row strip).
// acc[rb][cb] is a 16x16 fragment; C layout: col = lane&15, row = (lane>>4)*4+reg.
// G = hiA*hiB + hiA*loB + loA*hiB  (lo*lo dropped, ~2^-18 relative).
// ---------------------------------------------------------------------------
__device__ __forceinline__ void gram_tile(
    const ushort* __restrict__ hHi, const ushort* __restrict__ hLo,
    int bi, int bj, int wave, int r16, int kb, f32x4 acc[2][8])
{
#pragma unroll
    for (int rb = 0; rb < 2; ++rb)
#pragma unroll
        for (int cb = 0; cb < 8; ++cb) acc[rb][cb] = (f32x4){0.f, 0.f, 0.f, 0.f};

    const int arow = bi * TILE + wave * 32 + r16;
    short8 Ah[2][2], Al[2][2];
#pragma unroll
    for (int rb = 0; rb < 2; ++rb)
#pragma unroll
        for (int ks = 0; ks < 2; ++ks) {
            Ah[rb][ks] = ldfrag(hHi, arow + rb * 16, ks * 32 + kb * 8);
            Al[rb][ks] = ldfrag(hLo, arow + rb * 16, ks * 32 + kb * 8);
        }

    const int brow = bj * TILE + r16;
#pragma unroll
    for (int cb = 0; cb < 8; ++cb) {
        short8 Bh[2], Bl[2];
#pragma unroll
        for (int ks = 0; ks < 2; ++ks) {
            Bh[ks] = ldfrag(hHi, brow + cb * 16, ks * 32 + kb * 8);
            Bl[ks] = ldfrag(hLo, brow + cb * 16, ks * 32 + kb * 8);
        }
#pragma unroll
        for (int rb = 0; rb < 2; ++rb)
#pragma unroll
            for (int ks = 0; ks < 2; ++ks) {
                acc[rb][cb] = __builtin_amdgcn_mfma_f32_16x16x32_bf16(Ah[rb][ks], Bh[ks], acc[rb][cb], 0, 0, 0);
                acc[rb][cb] = __builtin_amdgcn_mfma_f32_16x16x32_bf16(Ah[rb][ks], Bl[ks], acc[rb][cb], 0, 0, 0);
                acc[rb][cb] = __builtin_amdgcn_mfma_f32_16x16x32_bf16(Al[rb][ks], Bh[ks], acc[rb][cb], 0, 0, 0);
            }
    }
}

// ---------------------------------------------------------------------------
// Kernel 2: symmetric pass 1, dense triangle grid with balanced XCD banding.
// Column pairs (P, 127-P) have (P+1)+(128-P) = 129 blocks; XCD k owns pairs
// [8k, 8k+8) -> exactly 1032 blocks and a 16-column (512 KB) B working set
// that stays L2-resident. Emits per-row (tile max, tile sum-exp) partials.
// ---------------------------------------------------------------------------
__global__ __launch_bounds__(256) void pass1_mfma(
    const ushort* __restrict__ hHi, const ushort* __restrict__ hLo,
    float* __restrict__ part_m, float* __restrict__ part_l)
{
    // triangle decode: p -> (bi <= bj)
    const int p = blockIdx.x;
    const int xcd = p & 7, s = p >> 3;        // s in [0, 1032)
    const int q = s / 129, r = s % 129;       // q in [0,8)
    const int P = xcd * 8 + q;                // pair id in [0,64)
    int bi, bj;
    if (r <= P) { bi = r;         bj = P;       }
    else        { bi = r - P - 1; bj = 127 - P; }

    __shared__ float jm[4][128], jl[4][128];

    const int tid = threadIdx.x;
    const int wave = tid >> 6, lane = tid & 63;
    const int r16 = lane & 15, kb = lane >> 4;

    f32x4 acc[2][8];
    gram_tile(hHi, hLo, bi, bj, wave, r16, kb, acc);

    // ---- i-side: rows of tile bi (this thread's 8 rows) over 128 cols ----
#pragma unroll
    for (int rb = 0; rb < 2; ++rb) {
#pragma unroll
        for (int reg = 0; reg < 4; ++reg) {
            float m = acc[rb][0][reg];
#pragma unroll
            for (int cb = 1; cb < 8; ++cb) m = fmaxf(m, acc[rb][cb][reg]);
            m = fmaxf(m, __shfl_xor(m, 1));
            m = fmaxf(m, __shfl_xor(m, 2));
            m = fmaxf(m, __shfl_xor(m, 4));
            m = fmaxf(m, __shfl_xor(m, 8));
            float sum = 0.f;
#pragma unroll
            for (int cb = 0; cb < 8; ++cb) sum += __expf(acc[rb][cb][reg] - m);
            sum += __shfl_xor(sum, 1);
            sum += __shfl_xor(sum, 2);
            sum += __shfl_xor(sum, 4);
            sum += __shfl_xor(sum, 8);
            if (r16 == 0) {
                const int grow = bi * TILE + wave * 32 + rb * 16 + kb * 4 + reg;
                part_m[(size_t)bj * N + grow] = m;
                part_l[(size_t)bj * N + grow] = sum;
            }
        }
    }

    // ---- j-side: rows of tile bj (tile columns) over cols of tile bi ----
    if (bi != bj) {
#pragma unroll
        for (int cb = 0; cb < 8; ++cb) {
            float m = acc[0][cb][0];
#pragma unroll
            for (int rb = 0; rb < 2; ++rb)
#pragma unroll
                for (int reg = 0; reg < 4; ++reg) m = fmaxf(m, acc[rb][cb][reg]);
            m = fmaxf(m, __shfl_xor(m, 16));
            m = fmaxf(m, __shfl_xor(m, 32));
            float sum = 0.f;
#pragma unroll
            for (int rb = 0; rb < 2; ++rb)
#pragma unroll
                for (int reg = 0; reg < 4; ++reg) sum += __expf(acc[rb][cb][reg] - m);
            sum += __shfl_xor(sum, 16);
            sum += __shfl_xor(sum, 32);
            if (kb == 0) { jm[wave][cb * 16 + r16] = m; jl[wave][cb * 16 + r16] = sum; }
        }
        __syncthreads();
        if (tid < 128) {
            float M = jm[0][tid];
#pragma unroll
            for (int w = 1; w < 4; ++w) M = fmaxf(M, jm[w][tid]);
            float L = 0.f;
#pragma unroll
            for (int w = 0; w < 4; ++w) L += jl[w][tid] * __expf(jm[w][tid] - M);
            part_m[(size_t)bi * N + bj * TILE + tid] = M;
            part_l[(size_t)bi * N + bj * TILE + tid] = L;
        }
    }
}

// ---------------------------------------------------------------------------
// Kernel 3: merge 128 partial (m,l) per row -> rowmax m_i, r_i = 1/L.
// ---------------------------------------------------------------------------
__global__ __launch_bounds__(256) void merge_kernel(
    const float* __restrict__ part_m, const float* __restrict__ part_l,
    float* __restrict__ mrow, float* __restrict__ rrow)
{
    const int i = blockIdx.x * 256 + threadIdx.x;
    float M = -3.0e38f;
    for (int o = 0; o < NT; ++o) M = fmaxf(M, part_m[(size_t)o * N + i]);
    float L = 0.f;
    for (int o = 0; o < NT; ++o)
        L = fmaf(part_l[(size_t)o * N + i], __expf(part_m[(size_t)o * N + i] - M), L);
    mrow[i] = M;
    rrow[i] = 1.0f / L;
}

// ---------------------------------------------------------------------------
// Kernel 4: pass 2, 1D grid with XCD column banding: XCD k owns bj band
// [16k, 16k+16) (512 KB of h-panels, L2-resident) and streams bi. Recompute
// tile with MFMA, apply exp(g-m)*r, stage P-tile in LDS, write contiguous
// 512B/wave float4 nontemporal stores.
// ---------------------------------------------------------------------------
__global__ __launch_bounds__(256) void pass2_mfma(
    const ushort* __restrict__ hHi, const ushort* __restrict__ hLo,
    const float* __restrict__ mrow, const float* __restrict__ rrow,
    float* __restrict__ out)
{
    const int p = blockIdx.x;
    const int xcd = p & 7, slot = p >> 3;          // slot in [0, 2048)
    const int bj = xcd * 16 + (slot & 15);
    const int bi = slot >> 4;

    const int tid = threadIdx.x;
    const int wave = tid >> 6, lane = tid & 63;
    const int r16 = lane & 15, kb = lane >> 4;

    __shared__ float ldsP[64 * S2];

    f32x4 acc[2][8];
    gram_tile(hHi, hLo, bi, bj, wave, r16, kb, acc);

#pragma unroll
    for (int hh = 0; hh < 2; ++hh) {
        if ((wave >> 1) == hh) {  // waves 2hh,2hh+1 own rows [hh*64, hh*64+64)
#pragma unroll
            for (int rb = 0; rb < 2; ++rb)
#pragma unroll
                for (int reg = 0; reg < 4; ++reg) {
                    const int rtile = wave * 32 + rb * 16 + kb * 4 + reg;
                    const int grow  = bi * TILE + rtile;
                    const float m = mrow[grow];
                    const float rr = rrow[grow];
                    const int rl = rtile - hh * 64;
#pragma unroll
                    for (int cb = 0; cb < 8; ++cb)
                        ldsP[rl * S2 + cb * 16 + r16] = __expf(acc[rb][cb][reg] - m) * rr;
                }
        }
        __syncthreads();
        // coalesced streaming store: 2048 float4 = 64 rows x 32 float4
#pragma unroll
        for (int q = 0; q < 8; ++q) {
            const int f4 = tid + 256 * q;
            const int rl = f4 >> 5, c4 = f4 & 31;
            const f32x4 v = *(const f32x4*)&ldsP[rl * S2 + c4 * 4];
            f32x4* dst = (f32x4*)(out + (size_t)(bi * TILE + hh * 64 + rl) * N + bj * TILE + c4 * 4);
            __builtin_nontemporal_store(v, dst);
        }
        __syncthreads();
    }
}

// ---------------------------------------------------------------------------
extern "C" void kernel_launch(void* const* d_in, const int* in_sizes, int n_in,
                              void* d_out, int out_size, void* d_ws, size_t ws_size,
                              hipStream_t stream)
{
    const float* data = (const float*)d_in[0];
    const float* W1   = (const float*)d_in[1];
    const float* b1   = (const float*)d_in[2];
    const float* W2   = (const float*)d_in[3];
    const float* b2   = (const float*)d_in[4];
    const float* W3   = (const float*)d_in[5];
    const float* b3   = (const float*)d_in[6];
    float* out = (float*)d_out;

    // workspace: part_m[NT*N] | part_l[NT*N] | mrow[N] | rrow[N] | hHi[N*64] | hLo[N*64]
    float* part_m = (float*)d_ws;
    float* part_l = part_m + (size_t)NT * N;
    float* mrow   = part_l + (size_t)NT * N;
    float* rrow   = mrow + N;
    ushort* hHi   = (ushort*)(rrow + N);
    ushort* hLo   = hHi + (size_t)N * DH;

    mlp_kernel<<<N / 128, 128, 0, stream>>>(data, W1, b1, W2, b2, W3, b3, hHi, hLo);
    pass1_mfma<<<NT * (NT + 1) / 2, 256, 0, stream>>>(hHi, hLo, part_m, part_l);
    merge_kernel<<<N / 256, 256, 0, stream>>>(part_m, part_l, mrow, rrow);
    pass2_mfma<<<NT * NT, 256, 0, stream>>>(hHi, hLo, mrow, rrow, out);
}